// Round 1
// baseline (787.379 us; speedup 1.0000x reference)
//
#include <hip/hip_runtime.h>
#include <hip/hip_bf16.h>

typedef __attribute__((ext_vector_type(4))) float f32x4;
typedef __bf16 bf16x8 __attribute__((ext_vector_type(8)));

#define TOKENS 16384
#define DIM    2048
#define NKVQ   3072

__device__ __forceinline__ void gload_lds16(const void* g, void* l) {
  __builtin_amdgcn_global_load_lds((const __attribute__((address_space(1))) void*)g,
                                   (__attribute__((address_space(3))) void*)l, 16, 0, 0);
}

// ---------------- cast fp32 -> bf16, 8 elems/thread ----------------
__global__ void cast8_kernel(const float* __restrict__ src, __bf16* __restrict__ dst, int n8) {
  int i = blockIdx.x * blockDim.x + threadIdx.x;
  if (i >= n8) return;
  const float4* s = (const float4*)src;
  float4 a = s[2 * i], b = s[2 * i + 1];
  bf16x8 o;
  o[0] = (__bf16)a.x; o[1] = (__bf16)a.y; o[2] = (__bf16)a.z; o[3] = (__bf16)a.w;
  o[4] = (__bf16)b.x; o[5] = (__bf16)b.y; o[6] = (__bf16)b.z; o[7] = (__bf16)b.w;
  ((bf16x8*)dst)[i] = o;
}

// ---------------- Weff[d, h*64+k] = sum_v Wo[d, h*64+v] * mem[h,k,v] ----------------
__global__ void weff_kernel(const float* __restrict__ Wo, const float* __restrict__ mem,
                            __bf16* __restrict__ Weff) {
  int idx = blockIdx.x * blockDim.x + threadIdx.x;  // 2048*1024
  int d = idx >> 10, hk = idx & 1023, h = hk >> 6;
  const float* wo = Wo + d * 1024 + h * 64;
  const float* mm = mem + hk * 64;
  float s = 0.f;
  #pragma unroll 8
  for (int v = 0; v < 64; ++v) s += wo[v] * mm[v];
  Weff[idx] = (__bf16)s;
}

// ---------------- core 128x128 bf16 MFMA tile (C = A @ B^T), m97 structure ----------------
template <int KTOT>
__device__ __forceinline__ void gemm_tile(const __bf16* __restrict__ A, int lda,
                                          const __bf16* __restrict__ Bw, int ldb,
                                          int m0, int n0, __bf16* As, __bf16* Bs,
                                          f32x4 acc[4][4]) {
  const int tid = threadIdx.x, wid = tid >> 6, lane = tid & 63;
  const int wr = wid >> 1, wc = wid & 1;
  const int lrow = lane & 15, lk = (lane >> 4) * 8;
  const int srow = lane >> 3, scol = (lane & 7) * 8;
  for (int k0 = 0; k0 < KTOT; k0 += 64) {
    __syncthreads();  // previous tile fully consumed before overwrite
    #pragma unroll
    for (int r = 0; r < 4; ++r) {
      const int chunk = wid * 4 + r;       // 16 chunks x 8 rows x 64 cols
      const int row = chunk * 8 + srow;
      gload_lds16(A  + (size_t)(m0 + row) * lda + k0 + scol, As + chunk * 512);
      gload_lds16(Bw + (size_t)(n0 + row) * ldb + k0 + scol, Bs + chunk * 512);
    }
    asm volatile("s_waitcnt vmcnt(0)" ::: "memory");
    __syncthreads();
    #pragma unroll
    for (int kk = 0; kk < 64; kk += 32) {
      bf16x8 af[4], bf_[4];
      #pragma unroll
      for (int m = 0; m < 4; ++m)
        af[m] = *(const bf16x8*)(As + (wr * 64 + m * 16 + lrow) * 64 + kk + lk);
      #pragma unroll
      for (int n = 0; n < 4; ++n)
        bf_[n] = *(const bf16x8*)(Bs + (wc * 64 + n * 16 + lrow) * 64 + kk + lk);
      #pragma unroll
      for (int m = 0; m < 4; ++m)
        #pragma unroll
        for (int n = 0; n < 4; ++n)
          acc[m][n] = __builtin_amdgcn_mfma_f32_16x16x32_bf16(af[m], bf_[n], acc[m][n], 0, 0, 0);
    }
  }
  __syncthreads();
}

// ---------------- GEMM 1: Y[16384 x 3072] = Xb @ [Wk;Wv;Wq]^T (bf16 out) ----------------
__global__ void __launch_bounds__(256)
gemm_kvq_kernel(const __bf16* __restrict__ Xb, const __bf16* __restrict__ Wkvq,
                __bf16* __restrict__ Y) {
  __shared__ __attribute__((aligned(16))) __bf16 As[128 * 64];
  __shared__ __attribute__((aligned(16))) __bf16 Bs[128 * 64];
  const int bm = blockIdx.x / 24, bn = blockIdx.x % 24;
  f32x4 acc[4][4] = {};
  gemm_tile<2048>(Xb, DIM, Wkvq, DIM, bm * 128, bn * 128, As, Bs, acc);
  const int tid = threadIdx.x, wid = tid >> 6, lane = tid & 63;
  const int wr = wid >> 1, wc = wid & 1;
  const int crow = (lane >> 4) * 4, ccol = lane & 15;
  #pragma unroll
  for (int m = 0; m < 4; ++m)
    #pragma unroll
    for (int n = 0; n < 4; ++n)
      #pragma unroll
      for (int r = 0; r < 4; ++r) {
        int row = bm * 128 + wr * 64 + m * 16 + crow + r;
        int col = bn * 128 + wc * 64 + n * 16 + ccol;
        Y[(size_t)row * NKVQ + col] = (__bf16)acc[m][n][r];
      }
}

// ---------------- GEMM 2: out = hidden + sigmoid(Xb@Wg^T) * (Q@Weff^T) ----------------
__global__ void __launch_bounds__(256)
gemm_out_kernel(const __bf16* __restrict__ Xb, const __bf16* __restrict__ Wgb,
                const __bf16* __restrict__ Yq, const __bf16* __restrict__ Weff,
                const float* __restrict__ hidden, float* __restrict__ out) {
  __shared__ __attribute__((aligned(16))) __bf16 As[128 * 64];
  __shared__ __attribute__((aligned(16))) __bf16 Bs[128 * 64];
  const int bm = blockIdx.x >> 4, bn = blockIdx.x & 15;
  f32x4 accg[4][4] = {};
  gemm_tile<2048>(Xb, DIM, Wgb, DIM, bm * 128, bn * 128, As, Bs, accg);
  #pragma unroll
  for (int m = 0; m < 4; ++m)
    #pragma unroll
    for (int n = 0; n < 4; ++n)
      #pragma unroll
      for (int r = 0; r < 4; ++r)
        accg[m][n][r] = 1.0f / (1.0f + __expf(-accg[m][n][r]));
  f32x4 accp[4][4] = {};
  gemm_tile<1024>(Yq, NKVQ, Weff, 1024, bm * 128, bn * 128, As, Bs, accp);
  const int tid = threadIdx.x, wid = tid >> 6, lane = tid & 63;
  const int wr = wid >> 1, wc = wid & 1;
  const int crow = (lane >> 4) * 4, ccol = lane & 15;
  #pragma unroll
  for (int m = 0; m < 4; ++m)
    #pragma unroll
    for (int n = 0; n < 4; ++n)
      #pragma unroll
      for (int r = 0; r < 4; ++r) {
        int row = bm * 128 + wr * 64 + m * 16 + crow + r;
        int col = bn * 128 + wc * 64 + n * 16 + ccol;
        size_t idx = (size_t)row * DIM + col;
        out[idx] = hidden[idx] + accg[m][n][r] * accp[m][n][r];
      }
}

// ---------------- memory update partials: part[sp][h] += K_h^T V_h over 1024 tokens ----------------
__global__ void __launch_bounds__(256)
mem_update_kernel(const __bf16* __restrict__ Y, float* __restrict__ part) {
  const int h = blockIdx.x & 15, sp = blockIdx.x >> 4;
  __shared__ __attribute__((aligned(16))) __bf16 KT[64 * 32];  // [kdim][token]
  __shared__ __attribute__((aligned(16))) __bf16 VT[64 * 32];  // [vdim][token]
  const int tid = threadIdx.x, wid = tid >> 6, lane = tid & 63;
  const int lrow = lane & 15, lk = (lane >> 4) * 8;
  const __bf16* Kbase = Y + (size_t)sp * 1024 * NKVQ + h * 64;
  const __bf16* Vbase = Kbase + 1024;
  f32x4 acc[4] = {};
  const int t = tid >> 3, c8 = (tid & 7) * 8;
  for (int t0 = 0; t0 < 1024; t0 += 32) {
    __syncthreads();
    bf16x8 kv = *(const bf16x8*)(Kbase + (size_t)(t0 + t) * NKVQ + c8);
    bf16x8 vv = *(const bf16x8*)(Vbase + (size_t)(t0 + t) * NKVQ + c8);
    #pragma unroll
    for (int j = 0; j < 8; ++j) {
      KT[(c8 + j) * 32 + t] = kv[j];
      VT[(c8 + j) * 32 + t] = vv[j];
    }
    __syncthreads();
    bf16x8 af = *(const bf16x8*)(KT + (wid * 16 + lrow) * 32 + lk);
    #pragma unroll
    for (int n = 0; n < 4; ++n) {
      bf16x8 bf_ = *(const bf16x8*)(VT + (n * 16 + lrow) * 32 + lk);
      acc[n] = __builtin_amdgcn_mfma_f32_16x16x32_bf16(af, bf_, acc[n], 0, 0, 0);
    }
  }
  float* pp = part + ((size_t)sp * 16 + h) * 4096;
  const int crow = wid * 16 + (lane >> 4) * 4, ccol = lane & 15;
  #pragma unroll
  for (int n = 0; n < 4; ++n)
    #pragma unroll
    for (int r = 0; r < 4; ++r)
      pp[(crow + r) * 64 + n * 16 + ccol] = acc[n][r];
}

// ---------------- memory reduce: out = 0.99*mem + sum_sp part ----------------
__global__ void mem_reduce_kernel(const float* __restrict__ part, const float* __restrict__ mem,
                                  float* __restrict__ out) {
  int i = blockIdx.x * blockDim.x + threadIdx.x;  // 65536
  float s = 0.99f * mem[i];
  #pragma unroll
  for (int sp = 0; sp < 16; ++sp) s += part[sp * 65536 + i];
  out[i] = s;
}

extern "C" void kernel_launch(void* const* d_in, const int* in_sizes, int n_in,
                              void* d_out, int out_size, void* d_ws, size_t ws_size,
                              hipStream_t stream) {
  const float* hidden = (const float*)d_in[0];
  const float* memory = (const float*)d_in[1];
  const float* Wk = (const float*)d_in[2];
  const float* Wv = (const float*)d_in[3];
  const float* Wq = (const float*)d_in[4];
  const float* Wg = (const float*)d_in[5];
  const float* Wo = (const float*)d_in[6];
  float* out = (float*)d_out;
  float* mem_out = out + (size_t)TOKENS * DIM;  // 33,554,432 floats in, then 65,536

  char* ws = (char*)d_ws;
  __bf16* Xb   = (__bf16*)(ws);                    // 16384x2048  (67,108,864 B)
  __bf16* Wkvq = (__bf16*)(ws + 67108864);         // 3072x2048   (12,582,912 B)
  __bf16* Wgb  = (__bf16*)(ws + 79691776);         // 2048x2048   ( 8,388,608 B)
  __bf16* Weff = (__bf16*)(ws + 88080384);         // 2048x1024   ( 4,194,304 B)
  __bf16* Yb   = (__bf16*)(ws + 92274688);         // 16384x3072  (100,663,296 B)
  float*  part = (float*)(ws + 192937984);         // 16x16x64x64 ( 4,194,304 B)

  // casts
  cast8_kernel<<<16384, 256, 0, stream>>>(hidden, Xb, 4194304);
  cast8_kernel<<<1024, 256, 0, stream>>>(Wk, Wkvq, 262144);
  cast8_kernel<<<1024, 256, 0, stream>>>(Wv, Wkvq + 2097152, 262144);
  cast8_kernel<<<1024, 256, 0, stream>>>(Wq, Wkvq + 4194304, 262144);
  cast8_kernel<<<2048, 256, 0, stream>>>(Wg, Wgb, 524288);
  weff_kernel<<<8192, 256, 0, stream>>>(Wo, memory, Weff);

  // big GEMMs
  gemm_kvq_kernel<<<128 * 24, 256, 0, stream>>>(Xb, Wkvq, Yb);
  gemm_out_kernel<<<128 * 16, 256, 0, stream>>>(Xb, Wgb, Yb + 2048, Weff, hidden, out);

  // memory update
  mem_update_kernel<<<256, 256, 0, stream>>>(Yb, part);
  mem_reduce_kernel<<<256, 256, 0, stream>>>(part, memory, mem_out);
}